// Round 15
// baseline (2339.725 us; speedup 1.0000x reference)
//
#include <hip/hip_runtime.h>

#define Bq 16
#define Cc 128
#define Tt 4096
#define Qq 8
#define Kk 1024
#define Nn (Bq*Tt)   // 65536 rows

#define ROWS 128     // rows per block
#define NTC  512     // codes per N-tile
#define KCH  32      // k-chunk staged in LDS
#define NTILES (Kk/NTC)    // 2
#define KCHUNKS (Cc/KCH)   // 4
#define NCHUNK (NTILES*KCHUNKS)  // 8

typedef float f32x4 __attribute__((ext_vector_type(4)));
typedef float f32x8 __attribute__((ext_vector_type(8)));
typedef int   i32x8 __attribute__((ext_vector_type(8)));

static __device__ __forceinline__ f32x4 splat4(float x) {
    f32x4 v = {x, x, x, x};
    return v;
}
static __device__ __forceinline__ f32x8 splat8f(float x) {
    f32x8 v = {x, x, x, x, x, x, x, x};
    return v;
}

// ws layout: [0..7] double closs; [64..) float ee[Q*K]
__global__ __launch_bounds__(256) void ee_kernel(const float* __restrict__ emb,
                                                 float* __restrict__ ee,
                                                 double* __restrict__ closs) {
    int i = blockIdx.x * 256 + threadIdx.x;
    if (i == 0) *closs = 0.0;
    if (i < Qq * Kk) {
        const float* e = emb + (size_t)i * Cc;
        float s0 = 0.f, s1 = 0.f, s2 = 0.f, s3 = 0.f;
#pragma unroll
        for (int c = 0; c < Cc; c += 4) {
            s0 = fmaf(e[c],     e[c],     s0);
            s1 = fmaf(e[c + 1], e[c + 1], s1);
            s2 = fmaf(e[c + 2], e[c + 2], s2);
            s3 = fmaf(e[c + 3], e[c + 3], s3);
        }
        ee[i] = (s0 + s1) + (s2 + s3);
    }
}

// 1024-thread block (16 waves/CU = 4/SIMD), 128 rows per block, all 8 stages
// fused. tx=t&63, ty=t>>6: ty is WAVE-UNIFORM -> A-read is a single-address
// 32B broadcast; B-read is 64 contiguous 16B lanes (conflict-free). B (codes)
// single-buffered 32k x 512c with async-split staging (issue loads -> compute
// -> barrier -> ds_write -> barrier). Accs = 16 named f32x4 (lo/hi quads),
// no vector concat. First-min argmin: ascending-k in-thread fold + 64-lane
// (d,k)-lexicographic shfl_xor reduce.
__global__ __launch_bounds__(1024, 4) void vq_kernel(
    const float* __restrict__ latents,
    const float* __restrict__ emb,
    const float* __restrict__ ee,
    float* __restrict__ quantized,
    float* __restrict__ codes,
    double* __restrict__ closs)
{
    extern __shared__ float smem[];
    float* r_lds  = smem;                        // [128][128] 64KB (k-major)
    float* B_lds  = smem + Cc * ROWS;            // [32][512] 64KB
    float* rrp    = B_lds + KCH * NTC;           // [8][128]
    float* rr_lds = rrp + 8 * ROWS;              // [128]
    int*   win    = (int*)(rr_lds + ROWS);       // [128]

    const int t   = threadIdx.x;
    const int tx  = t & 63;        // code-group (8 codes: 4 lo + 4 hi)
    const int ty  = t >> 6;        // row-group (8 rows), wave-uniform
    const int un  = t & 127;       // row for init/update phases
    const int ukg = t >> 7;        // k-octant (16 k each)
    const int cl  = t >> 1;        // staging: code 0..511
    const int hk  = (t & 1) * 16;  // staging: k-half of chunk

    const int rowbase = blockIdx.x * ROWS;
    const int bb  = rowbase >> 12;        // 128 | 4096: one batch per block
    const int tt0 = rowbase & (Tt - 1);

    // ---- init: r = latents (transposed into [k][row]), rr = ||r||^2 ----
    {
        const float* lb = latents + (size_t)bb * Cc * Tt + tt0 + un;
        float part = 0.f;
#pragma unroll
        for (int j = 0; j < 16; ++j) {
            int k = ukg * 16 + j;
            float v = lb[(size_t)k * Tt];
            r_lds[k * ROWS + un] = v;
            part = fmaf(v, v, part);
        }
        rrp[ukg * ROWS + un] = part;
    }
    __syncthreads();
    if (t < ROWS)
        rr_lds[t] = ((rrp[t] + rrp[ROWS + t]) + (rrp[2*ROWS + t] + rrp[3*ROWS + t]))
                  + ((rrp[4*ROWS + t] + rrp[5*ROWS + t]) + (rrp[6*ROWS + t] + rrp[7*ROWS + t]));
    __syncthreads();

    for (int q = 0; q < Qq; ++q) {
        const float* eq = emb + (size_t)q * Kk * Cc;

        f32x8 best_ = splat8f(3.4e38f);
        i32x8 bk_   = {0, 0, 0, 0, 0, 0, 0, 0};
        f32x8 rr8   = *(const f32x8*)&rr_lds[ty * 8];

        // prologue: stage chunk 0 (nt=0, kc=0)
        {
            const float* src = eq + (size_t)cl * Cc + hk;
            f32x4 pf0 = *(const f32x4*)(src);
            f32x4 pf1 = *(const f32x4*)(src + 4);
            f32x4 pf2 = *(const f32x4*)(src + 8);
            f32x4 pf3 = *(const f32x4*)(src + 12);
#pragma unroll
            for (int i2 = 0; i2 < 4; ++i2) B_lds[(hk +      i2) * NTC + cl] = pf0[i2];
#pragma unroll
            for (int i2 = 0; i2 < 4; ++i2) B_lds[(hk +  4 + i2) * NTC + cl] = pf1[i2];
#pragma unroll
            for (int i2 = 0; i2 < 4; ++i2) B_lds[(hk +  8 + i2) * NTC + cl] = pf2[i2];
#pragma unroll
            for (int i2 = 0; i2 < 4; ++i2) B_lds[(hk + 12 + i2) * NTC + cl] = pf3[i2];
        }
        __syncthreads();

        f32x4 aL0, aL1, aL2, aL3, aL4, aL5, aL6, aL7;
        f32x4 aH0, aH1, aH2, aH3, aH4, aH5, aH6, aH7;

        for (int id = 0; id < NCHUNK; ++id) {
            const int nt = id >> 2;
            const int kc = id & 3;
            if (kc == 0) {
                aL0 = splat4(0.f); aL1 = splat4(0.f); aL2 = splat4(0.f); aL3 = splat4(0.f);
                aL4 = splat4(0.f); aL5 = splat4(0.f); aL6 = splat4(0.f); aL7 = splat4(0.f);
                aH0 = splat4(0.f); aH1 = splat4(0.f); aH2 = splat4(0.f); aH3 = splat4(0.f);
                aH4 = splat4(0.f); aH5 = splat4(0.f); aH6 = splat4(0.f); aH7 = splat4(0.f);
            }

            // async-split: issue next chunk's global loads now...
            f32x4 pf0, pf1, pf2, pf3;
            if (id < NCHUNK - 1) {
                const int nid = id + 1;
                const float* src = eq + (size_t)(((nid >> 2) * NTC) + cl) * Cc
                                 + (nid & 3) * KCH + hk;
                pf0 = *(const f32x4*)(src);
                pf1 = *(const f32x4*)(src + 4);
                pf2 = *(const f32x4*)(src + 8);
                pf3 = *(const f32x4*)(src + 12);
            }

            // ...compute current chunk...
#pragma unroll 8
            for (int kk = 0; kk < KCH; ++kk) {
                f32x8 a_  = *(const f32x8*)&r_lds[(kc * KCH + kk) * ROWS + ty * 8];
                f32x4 blo = *(const f32x4*)&B_lds[kk * NTC + tx * 4];
                f32x4 bhi = *(const f32x4*)&B_lds[kk * NTC + 256 + tx * 4];
                aL0 = __builtin_elementwise_fma(splat4(a_[0]), blo, aL0);
                aH0 = __builtin_elementwise_fma(splat4(a_[0]), bhi, aH0);
                aL1 = __builtin_elementwise_fma(splat4(a_[1]), blo, aL1);
                aH1 = __builtin_elementwise_fma(splat4(a_[1]), bhi, aH1);
                aL2 = __builtin_elementwise_fma(splat4(a_[2]), blo, aL2);
                aH2 = __builtin_elementwise_fma(splat4(a_[2]), bhi, aH2);
                aL3 = __builtin_elementwise_fma(splat4(a_[3]), blo, aL3);
                aH3 = __builtin_elementwise_fma(splat4(a_[3]), bhi, aH3);
                aL4 = __builtin_elementwise_fma(splat4(a_[4]), blo, aL4);
                aH4 = __builtin_elementwise_fma(splat4(a_[4]), bhi, aH4);
                aL5 = __builtin_elementwise_fma(splat4(a_[5]), blo, aL5);
                aH5 = __builtin_elementwise_fma(splat4(a_[5]), bhi, aH5);
                aL6 = __builtin_elementwise_fma(splat4(a_[6]), blo, aL6);
                aH6 = __builtin_elementwise_fma(splat4(a_[6]), bhi, aH6);
                aL7 = __builtin_elementwise_fma(splat4(a_[7]), blo, aL7);
                aH7 = __builtin_elementwise_fma(splat4(a_[7]), bhi, aH7);
            }

            if (id < NCHUNK - 1) {
                __syncthreads();   // everyone done reading B_lds
#pragma unroll
                for (int i2 = 0; i2 < 4; ++i2) B_lds[(hk +      i2) * NTC + cl] = pf0[i2];
#pragma unroll
                for (int i2 = 0; i2 < 4; ++i2) B_lds[(hk +  4 + i2) * NTC + cl] = pf1[i2];
#pragma unroll
                for (int i2 = 0; i2 < 4; ++i2) B_lds[(hk +  8 + i2) * NTC + cl] = pf2[i2];
#pragma unroll
                for (int i2 = 0; i2 < 4; ++i2) B_lds[(hk + 12 + i2) * NTC + cl] = pf3[i2];
                __syncthreads();   // B ready
            }

            if (kc == 3) {
                // fold tile nt: d = (rr - 2*dot) + ee  (reference association)
                const int kb = nt * NTC + tx * 4;
                f32x4 eelo = *(const f32x4*)(ee + q * Kk + kb);
                f32x4 eehi = *(const f32x4*)(ee + q * Kk + kb + 256);
#define FOLD_ROW(I_) {                                                        \
                f32x4 dl = __builtin_elementwise_fma(splat4(-2.0f), aL##I_,   \
                                                     splat4(rr8[I_])) + eelo; \
                _Pragma("unroll")                                             \
                for (int c = 0; c < 4; ++c) {                                 \
                    float d = dl[c];                                          \
                    bool lt = d < best_[I_];                                  \
                    best_[I_] = lt ? d : best_[I_];                           \
                    bk_[I_]   = lt ? (kb + c) : bk_[I_];                      \
                }                                                             \
                f32x4 dh = __builtin_elementwise_fma(splat4(-2.0f), aH##I_,   \
                                                     splat4(rr8[I_])) + eehi; \
                _Pragma("unroll")                                             \
                for (int c = 0; c < 4; ++c) {                                 \
                    float d = dh[c];                                          \
                    bool lt = d < best_[I_];                                  \
                    best_[I_] = lt ? d : best_[I_];                           \
                    bk_[I_]   = lt ? (kb + 256 + c) : bk_[I_];                \
                } }
                FOLD_ROW(0) FOLD_ROW(1) FOLD_ROW(2) FOLD_ROW(3)
                FOLD_ROW(4) FOLD_ROW(5) FOLD_ROW(6) FOLD_ROW(7)
#undef FOLD_ROW
            }
        } // chunks

        // 64-lane reduce (whole wave shares a row-group); (d,k) lexicographic
#pragma unroll
        for (int m = 1; m < 64; m <<= 1) {
#pragma unroll
            for (int i = 0; i < 8; ++i) {
                float od = __shfl_xor(best_[i], m);
                int   ok = __shfl_xor(bk_[i], m);
                bool rep = (od < best_[i]) || (od == best_[i] && ok < bk_[i]);
                best_[i] = rep ? od : best_[i];
                bk_[i]   = rep ? ok : bk_[i];
            }
        }
        if (tx == 0) {
#pragma unroll
            for (int i = 0; i < 8; ++i) {
                int row = ty * 8 + i;
                win[row] = bk_[i];
                codes[((size_t)bb * Qq + q) * Tt + tt0 + row] = (float)bk_[i];
            }
        }
        __syncthreads();

        // update: r -= e[win]; recompute rr
        {
            const float* er = eq + (size_t)win[un] * Cc + ukg * 16;
            float part = 0.f;
#pragma unroll
            for (int j = 0; j < 4; ++j) {
                f32x4 ev = *(const f32x4*)(er + j * 4);
#pragma unroll
                for (int i2 = 0; i2 < 4; ++i2) {
                    int k = ukg * 16 + j * 4 + i2;
                    float rv = r_lds[k * ROWS + un] - ev[i2];
                    r_lds[k * ROWS + un] = rv;
                    part = fmaf(rv, rv, part);
                }
            }
            rrp[ukg * ROWS + un] = part;
        }
        __syncthreads();
        if (t < ROWS)
            rr_lds[t] = ((rrp[t] + rrp[ROWS + t]) + (rrp[2*ROWS + t] + rrp[3*ROWS + t]))
                      + ((rrp[4*ROWS + t] + rrp[5*ROWS + t]) + (rrp[6*ROWS + t] + rrp[7*ROWS + t]));
        __syncthreads();
        // closs: sum of new rr over the block's rows
        if (t < 64) {
            double s = (double)rr_lds[t] + (double)rr_lds[t + 64];
#pragma unroll
            for (int off = 32; off; off >>= 1)
                s += __shfl_down(s, off);
            if (t == 0) atomicAdd(closs, s);
        }
    } // q

    // epilogue: quantized = latents - r_final
    {
        const float* lb = latents + (size_t)bb * Cc * Tt + tt0 + un;
        float* qb = quantized + (size_t)bb * Cc * Tt + tt0 + un;
#pragma unroll
        for (int j = 0; j < 16; ++j) {
            int k = ukg * 16 + j;
            qb[(size_t)k * Tt] = lb[(size_t)k * Tt] - r_lds[k * ROWS + un];
        }
    }
}

__global__ void fin_kernel(const double* __restrict__ closs, float* __restrict__ loss_out) {
    loss_out[0] = (float)(*closs / (double)((size_t)Nn * Cc * Qq));
    loss_out[1] = 0.0f;
}

extern "C" void kernel_launch(void* const* d_in, const int* in_sizes, int n_in,
                              void* d_out, int out_size, void* d_ws, size_t ws_size,
                              hipStream_t stream) {
    const float* latents = (const float*)d_in[0];
    const float* emb     = (const float*)d_in[1];
    float* out       = (float*)d_out;
    float* quantized = out;                                   // B*C*T
    float* codes     = out + (size_t)Bq * Cc * Tt;            // B*Q*T
    float* loss      = codes + (size_t)Bq * Qq * Tt;          // 2 scalars
    double* closs    = (double*)d_ws;
    float*  ee       = (float*)((char*)d_ws + 64);

    const size_t smem = (size_t)(Cc * ROWS + KCH * NTC + 8 * ROWS + ROWS) * sizeof(float)
                      + ROWS * sizeof(int);   // 136192 B
    (void)hipFuncSetAttribute((const void*)vq_kernel,
                              hipFuncAttributeMaxDynamicSharedMemorySize, (int)smem);

    ee_kernel<<<(Qq * Kk + 255) / 256, 256, 0, stream>>>(emb, ee, closs);
    vq_kernel<<<Nn / ROWS, 1024, smem, stream>>>(latents, emb, ee, quantized, codes, closs);
    fin_kernel<<<1, 1, 0, stream>>>(closs, loss);
}